// Round 6
// baseline (783.003 us; speedup 1.0000x reference)
//
#include <hip/hip_runtime.h>
#include <hip/hip_fp16.h>
#include <math.h>

#define N_NODES 100000
#define N_EDGES 1600000
#define LN_EPS 1e-5f
#define NORM_EPS 1e-12f
#define ROWS_PER_BLOCK 32
#define GEMM_BLOCKS (N_NODES / ROWS_PER_BLOCK)            // 3125, exact
#define WSTRIDE 66   // even (b64-aligned) and 2c+k -> 2-way banks (free)
// R12/R13 ERRATA (measured): scattered partial-line stores pay a full 64B
// fetch+WB PER TOUCH whenever consecutive records of a line are written by
// different workgroups.  Invariant: coalescing happens ONLY when one block
// (one CU/L2) owns all writes to a line.  R14 (WIN 317->292): bucketed
// counting sort.  R15 (WIN 292->254): bucket-level histogram replaced the
// 1.6M random node atomics (they measured as +49.4MB WRITE / ~50us in gemm).
// R16: k_gather (77us, VALU 54%, HBM 24%) re-decoded a 51MB rec[] stream
// that k_place had just paid to write.  Fuse: k_place accumulates its own
// alphas into a 16KB LDS acc[64][64] (ds_add_f32) and runs the LN epilogue
// -> rec[], row_ptr and k_gather deleted; staged[] packed to 4B/edge.
#define WB 64                                   // nodes per place-bucket
#define NBKT ((N_NODES + WB - 1) / WB)          // 1563
#define BIN_TILE 8192                           // 1024 thr x 8 edges
#define BIN_BLOCKS ((N_EDGES + BIN_TILE - 1) / BIN_TILE)  // 196
#define QCHUNK 1024                             // staged-alpha queue depth

// ---------------------------------------------------------------------------
// K1: h = x @ W^T + b (N x 64) -> fp16 (|h|~6 << 65504; 8x less quant error
// than bf16); per-node attn scores fp32.  PURE GEMM (R15).  K-LOOP
// DELIBERATELY NOT UNROLLED (#pragma unroll 1): R5/R6 measured the unrolled
// version spilling acc[] at ANY VGPR budget.  No min-waves hint (R5).  NO
// nontemporal hints (R9).  NO cooperative launch (R10: grid.sync ~200us).
// ---------------------------------------------------------------------------
__global__ __launch_bounds__(256) void k_gemm(
    const float* __restrict__ x, const float* __restrict__ W,
    const float* __restrict__ b, const float* __restrict__ a,
    __half* __restrict__ h16,
    float* __restrict__ s_src, float* __restrict__ s_dst)
{
    __shared__ float WL[64 * WSTRIDE];            // WL[c*66 + k] = W[c][k]
    __shared__ float xs[ROWS_PER_BLOCK * 64];
    const int tid  = threadIdx.x;
    const int lane = tid & 63;
    const int wv   = tid >> 6;

    for (int idx = tid * 4; idx < 64 * 64; idx += 256 * 4) {
        const float4 w = *(const float4*)(W + idx);
        const int c = idx >> 6, k = idx & 63;
        WL[c * WSTRIDE + k + 0] = w.x;
        WL[c * WSTRIDE + k + 1] = w.y;
        WL[c * WSTRIDE + k + 2] = w.z;
        WL[c * WSTRIDE + k + 3] = w.w;
    }
    const int row0 = blockIdx.x * ROWS_PER_BLOCK;
    for (int idx = tid * 4; idx < ROWS_PER_BLOCK * 64; idx += 256 * 4)
        *(float4*)(xs + idx) = *(const float4*)(x + (size_t)row0 * 64 + idx);
    __syncthreads();

    const float bias = b[lane];
    float acc[8];
    #pragma unroll
    for (int r = 0; r < 8; ++r) acc[r] = bias;

    const int rbase = wv * 8;
    const float* wrow = WL + lane * WSTRIDE;
    const float* xrow = xs + rbase * 64;
    #pragma unroll 1   // DO NOT unroll: keeps live set small (see header)
    for (int kk = 0; kk < 64; kk += 4) {
        const float2 w01 = *(const float2*)(wrow + kk);
        const float2 w23 = *(const float2*)(wrow + kk + 2);
        #pragma unroll
        for (int r = 0; r < 8; ++r) {
            const float4 xq = *(const float4*)(xrow + r * 64 + kk);
            acc[r] += xq.x * w01.x + xq.y * w01.y + xq.z * w23.x + xq.w * w23.y;
        }
    }

    const float asrc = a[(lane >> 3) * 16 + (lane & 7)];
    const float adst = a[(lane >> 3) * 16 + 8 + (lane & 7)];
    #pragma unroll
    for (int r = 0; r < 8; ++r) {
        const int row = row0 + rbase + r;
        const float v = acc[r];
        h16[(size_t)row * 64 + lane] = __float2half_rn(v);
        float p = v * asrc, q = v * adst;
        p += __shfl_xor(p, 1);  q += __shfl_xor(q, 1);
        p += __shfl_xor(p, 2);  q += __shfl_xor(q, 2);
        p += __shfl_xor(p, 4);  q += __shfl_xor(q, 4);
        if ((lane & 7) == 0) {
            s_src[row * 8 + (lane >> 3)] = p;
            s_dst[row * 8 + (lane >> 3)] = q;
        }
    }
}

// ---------------------------------------------------------------------------
// k_hist: bucket-level (src>>6) histogram.  LDS compresses 8192 edges/block
// into <=1563 sequential global atomics (294K total).
// ---------------------------------------------------------------------------
__global__ __launch_bounds__(1024) void k_hist(
    const int* __restrict__ ei, int* __restrict__ bhist)
{
    __shared__ int hist[NBKT];
    const int tid = threadIdx.x;
    for (int b = tid; b < NBKT; b += 1024) hist[b] = 0;
    __syncthreads();
    const int e0 = blockIdx.x * BIN_TILE;
    #pragma unroll
    for (int j = 0; j < 8; ++j) {
        const int e = e0 + j * 1024 + tid;
        if (e < N_EDGES) atomicAdd(&hist[ei[e] >> 6], 1);
    }
    __syncthreads();
    for (int b = tid; b < NBKT; b += 1024)
        if (hist[b]) atomicAdd(&bhist[b], hist[b]);
}

// ---------------------------------------------------------------------------
// k_bscan: exclusive scan of the 1563 bucket counts -> bucket_base (segment
// bounds for k_place) + gbin (scatter frontiers for k_bin).
// ---------------------------------------------------------------------------
__global__ __launch_bounds__(1024) void k_bscan(
    const int* __restrict__ bhist, int* __restrict__ bucket_base,
    int* __restrict__ gbin)
{
    __shared__ int wsum[16];
    const int tid = threadIdx.x, lane = tid & 63, wv = tid >> 6;

    int v = (tid < NBKT) ? bhist[tid] : 0;
    int sc = v;
    #pragma unroll
    for (int off = 1; off < 64; off <<= 1) {
        int t = __shfl_up(sc, off);
        if (lane >= off) sc += t;
    }
    if (lane == 63) wsum[wv] = sc;
    __syncthreads();
    if (tid < 16) {
        int ws = wsum[tid];
        #pragma unroll
        for (int off = 1; off < 16; off <<= 1) {
            int t = __shfl_up(ws, off);
            if (tid >= off) ws += t;
        }
        wsum[tid] = ws;
    }
    __syncthreads();
    const int pref0 = wv ? wsum[wv - 1] : 0;
    const int ex0 = pref0 + sc - v;
    if (tid < NBKT) { bucket_base[tid] = ex0; gbin[tid] = ex0; }
    const int T1 = wsum[15];
    __syncthreads();

    const int i2 = 1024 + tid;
    int v2 = (i2 < NBKT) ? bhist[i2] : 0;
    int sc2 = v2;
    #pragma unroll
    for (int off = 1; off < 64; off <<= 1) {
        int t = __shfl_up(sc2, off);
        if (lane >= off) sc2 += t;
    }
    if (lane == 63) wsum[wv] = sc2;
    __syncthreads();
    if (tid < 16) {
        int ws = wsum[tid];
        #pragma unroll
        for (int off = 1; off < 16; off <<= 1) {
            int t = __shfl_up(ws, off);
            if (tid >= off) ws += t;
        }
        wsum[tid] = ws;
    }
    __syncthreads();
    const int pref1 = wv ? wsum[wv - 1] : 0;
    const int ex1 = T1 + pref1 + sc2 - v2;
    if (i2 < NBKT) { bucket_base[i2] = ex1; gbin[i2] = ex1; }
    if (tid == 0) bucket_base[NBKT] = N_EDGES;
}

// ---------------------------------------------------------------------------
// k_bin: bucket edges by src>>6.  LDS histogram (atomic return = local
// rank), ONE global atomic per (block,bucket) claims a contiguous run, then
// each thread writes its packed word at base+rank.  R16: word = (src&63) |
// (dst<<6) -- 4B/edge, half of R14's int2 (src&63 == src-64g since bucket
// membership fixes src>>6; dst < 2^17).
// ---------------------------------------------------------------------------
__global__ __launch_bounds__(1024) void k_bin(
    const int* __restrict__ ei, int* __restrict__ gbin,
    unsigned int* __restrict__ staged)
{
    __shared__ int hist[NBKT];
    __shared__ int base[NBKT];
    const int tid = threadIdx.x;
    for (int b = tid; b < NBKT; b += 1024) hist[b] = 0;
    __syncthreads();

    int s[8], d[8], r[8];
    const int e0 = blockIdx.x * BIN_TILE;
    #pragma unroll
    for (int j = 0; j < 8; ++j) {
        const int e = e0 + j * 1024 + tid;
        if (e < N_EDGES) {
            s[j] = ei[e];
            d[j] = ei[N_EDGES + e];
            r[j] = atomicAdd(&hist[s[j] >> 6], 1);
        }
    }
    __syncthreads();
    for (int b = tid; b < NBKT; b += 1024)
        if (hist[b]) base[b] = atomicAdd(&gbin[b], hist[b]);
    __syncthreads();
    #pragma unroll
    for (int j = 0; j < 8; ++j) {
        const int e = e0 + j * 1024 + tid;
        if (e < N_EDGES)
            staged[(size_t)base[s[j] >> 6] + r[j]] =
                (unsigned int)((s[j] & 63) | (d[j] << 6));
    }
}

// ---------------------------------------------------------------------------
// k_place (R16, fused): block g owns nodes [g*64, g*64+64) and segment
// [bucket_base[g], bucket_base[g+1]).  Per 1024-edge chunk:
//   phase A: each thread computes its edge's softmax alpha (fp16x8-packed,
//            proven numerics) into an LDS queue.
//   phase B: wave-per-edge consume -- 64 lanes read the 128B h16[dst] row
//            coalesced and ds_add_f32 into acc[src&63][lane] (bank = lane&31,
//            2 lanes/bank = free).
// Epilogue: residual + LN + L2norm straight from LDS; out window (16KB) is
// block-exclusive per the R14 invariant.  rec[]/row_ptr/k_gather deleted.
// ---------------------------------------------------------------------------
__global__ __launch_bounds__(1024) void k_place(
    const int* __restrict__ bucket_base, const unsigned int* __restrict__ staged,
    const float* __restrict__ s_src, const float* __restrict__ s_dst,
    const __half* __restrict__ h16, const float* __restrict__ x,
    const float* __restrict__ ln_scale, const float* __restrict__ ln_bias,
    float* __restrict__ out)
{
    __shared__ float accs[WB * 64];          // 16 KB
    __shared__ uint4 qa[QCHUNK];             // 16 KB packed fp16 alpha
    __shared__ unsigned int qm[QCHUNK];      //  4 KB packed {srcl,dst}
    const int g    = blockIdx.x;
    const int n0   = g * WB;
    const int tid  = threadIdx.x;
    const int lane = tid & 63;
    const int wv   = tid >> 6;

    #pragma unroll
    for (int k = tid; k < WB * 64; k += 1024) accs[k] = 0.f;
    const int beg = bucket_base[g];
    const int end = bucket_base[g + 1];
    __syncthreads();

    for (int cb = beg; cb < end; cb += QCHUNK) {
        const int m = min(QCHUNK, end - cb);
        if (tid < m) {
            const unsigned int w = staged[cb + tid];
            const int src = n0 + (int)(w & 63u);
            const int dst = (int)(w >> 6);

            const float4 a0 = *(const float4*)(s_src + (size_t)src * 8);
            const float4 a1 = *(const float4*)(s_src + (size_t)src * 8 + 4);
            const float4 b0 = *(const float4*)(s_dst + (size_t)dst * 8);
            const float4 b1 = *(const float4*)(s_dst + (size_t)dst * 8 + 4);
            float sc[8] = {a0.x + b0.x, a0.y + b0.y, a0.z + b0.z, a0.w + b0.w,
                           a1.x + b1.x, a1.y + b1.y, a1.z + b1.z, a1.w + b1.w};
            float mx = -1e30f;
            #pragma unroll
            for (int h = 0; h < 8; ++h) {
                sc[h] = (sc[h] >= 0.f) ? sc[h] : 0.2f * sc[h];
                mx = fmaxf(mx, sc[h]);
            }
            float sum = 0.f;
            #pragma unroll
            for (int h = 0; h < 8; ++h) { sc[h] = __expf(sc[h] - mx); sum += sc[h]; }
            const float inv = 1.f / sum;
            unsigned int q[4];
            #pragma unroll
            for (int jj = 0; jj < 4; ++jj) {
                const unsigned short lo = __half_as_ushort(__float2half_rn(sc[2*jj]   * inv));
                const unsigned short hi = __half_as_ushort(__float2half_rn(sc[2*jj+1] * inv));
                q[jj] = (unsigned int)lo | ((unsigned int)hi << 16);
            }
            qa[tid] = make_uint4(q[0], q[1], q[2], q[3]);
            qm[tid] = w;
        }
        __syncthreads();

        const int k0 = wv * 64;
        const int kcnt = min(64, m - k0);
        for (int k = 0; k < kcnt; ++k) {
            const unsigned int w = qm[k0 + k];
            const float al = __half2float(
                ((const __half*)(qa + k0 + k))[lane >> 3]);
            const float hv = __half2float(h16[(size_t)(w >> 6) * 64 + lane]);
            atomicAdd(&accs[(w & 63u) * 64 + lane], al * hv);
        }
        __syncthreads();
    }

    // epilogue: residual + LayerNorm + L2 normalize (wave wv -> 4 nodes)
    #pragma unroll 1
    for (int r = 0; r < 4; ++r) {
        const int nl = wv * 4 + r;
        const int i  = n0 + nl;
        if (i >= N_NODES) continue;
        float v = accs[nl * 64 + lane] + x[(size_t)i * 64 + lane];
        float s = v;
        #pragma unroll
        for (int off = 1; off < 64; off <<= 1) s += __shfl_xor(s, off);
        const float mu = s * (1.f / 64.f);
        const float d = v - mu;
        float vs = d * d;
        #pragma unroll
        for (int off = 1; off < 64; off <<= 1) vs += __shfl_xor(vs, off);
        const float var = vs * (1.f / 64.f);
        float y = d * rsqrtf(var + LN_EPS) * ln_scale[lane] + ln_bias[lane];
        float ss = y * y;
        #pragma unroll
        for (int off = 1; off < 64; off <<= 1) ss += __shfl_xor(ss, off);
        const float norm = sqrtf(ss);
        out[(size_t)i * 64 + lane] = y / fmaxf(norm, NORM_EPS);
    }
}

// ---------------------------------------------------------------------------
extern "C" void kernel_launch(void* const* d_in, const int* in_sizes, int n_in,
                              void* d_out, int out_size, void* d_ws, size_t ws_size,
                              hipStream_t stream)
{
    const float* x        = (const float*)d_in[0];
    const int*   ei       = (const int*)d_in[1];
    const float* W        = (const float*)d_in[2];
    const float* b        = (const float*)d_in[3];
    const float* a        = (const float*)d_in[4];
    const float* ln_scale = (const float*)d_in[5];
    const float* ln_bias  = (const float*)d_in[6];
    float* out = (float*)d_out;

    char* ws = (char*)d_ws;
    size_t off = 0;
    auto alloc = [&](size_t bytes) {
        void* p = ws + off;
        off = (off + bytes + 255) & ~(size_t)255;
        return p;
    };
    __half* h16        = (__half*)alloc((size_t)N_NODES * 64 * 2);
    float*  s_src      = (float*) alloc((size_t)N_NODES * 8 * 4);
    float*  s_dst      = (float*) alloc((size_t)N_NODES * 8 * 4);
    int*    bhist      = (int*)   alloc((size_t)NBKT * 4);
    int*    bucket_base= (int*)   alloc((size_t)(NBKT + 1) * 4);
    int*    gbin       = (int*)   alloc((size_t)NBKT * 4);
    unsigned int* staged = (unsigned int*)alloc((size_t)N_EDGES * 4);

    hipMemsetAsync(bhist, 0, (size_t)NBKT * 4, stream);

    k_hist  <<<BIN_BLOCKS, 1024, 0, stream>>>(ei, bhist);
    k_bscan <<<1, 1024, 0, stream>>>(bhist, bucket_base, gbin);
    k_gemm  <<<GEMM_BLOCKS, 256, 0, stream>>>(x, W, b, a, h16, s_src, s_dst);
    k_bin   <<<BIN_BLOCKS, 1024, 0, stream>>>(ei, gbin, staged);
    k_place <<<NBKT, 1024, 0, stream>>>(bucket_base, staged, s_src, s_dst,
                                        h16, x, ln_scale, ln_bias, out);
}

// Round 7
// 234.692 us; speedup vs baseline: 3.3363x; 3.3363x over previous
//
#include <hip/hip_runtime.h>
#include <hip/hip_fp16.h>
#include <math.h>

#define N_NODES 100000
#define N_EDGES 1600000
#define LN_EPS 1e-5f
#define NORM_EPS 1e-12f
#define ROWS_PER_BLOCK 32
#define GEMM_BLOCKS (N_NODES / ROWS_PER_BLOCK)            // 3125, exact
#define WSTRIDE 66   // even (b64-aligned) and 2c+k -> 2-way banks (free)
// R12/R13 ERRATA (measured): scattered partial-line stores pay a full 64B
// fetch+WB PER TOUCH whenever consecutive records of a line are written by
// different workgroups.  Invariant: coalescing happens ONLY when one block
// (one CU/L2) owns all writes to a line.  R14 (WIN 317->292): bucketed
// counting sort.  R15 (WIN 292->254): bucket-level histogram replaced the
// 1.6M random node atomics (+49.4MB WRITE / ~50us in gemm).
// R16 ERRATA (FAILED 254->783): fusing gather into k_place as a barrier-
// synced LDS queue left ONE h16 load in flight per wave (VALU 6%, HBM 3%:
// pure latency serialization at 2 blocks/CU).  Gather needs the unrolled
// many-loads-in-flight, barrier-free wave structure.  REVERTED to R5.
// R17: gather was ~30 VALU ops/edge (54% VALUBusy math) -- mostly 64-bit
// record addressing.  Split rec into flat dst_sorted[]+alpha16[] streams
// (base+immediate addressing, 20B/edge), hoist lane/head bases, 32-bit
// indices, unroll 8.
#define WB 64                                   // nodes per place-bucket
#define NBKT ((N_NODES + WB - 1) / WB)          // 1563
#define BIN_TILE 8192                           // 1024 thr x 8 edges
#define BIN_BLOCKS ((N_EDGES + BIN_TILE - 1) / BIN_TILE)  // 196

// ---------------------------------------------------------------------------
// K1: h = x @ W^T + b (N x 64) -> fp16 (|h|~6 << 65504; 8x less quant error
// than bf16); per-node attn scores fp32.  PURE GEMM (R15).  K-LOOP
// DELIBERATELY NOT UNROLLED (#pragma unroll 1): R5/R6 measured the unrolled
// version spilling acc[] at ANY VGPR budget.  No min-waves hint (R5).  NO
// nontemporal hints (R9).  NO cooperative launch (R10: grid.sync ~200us).
// ---------------------------------------------------------------------------
__global__ __launch_bounds__(256) void k_gemm(
    const float* __restrict__ x, const float* __restrict__ W,
    const float* __restrict__ b, const float* __restrict__ a,
    __half* __restrict__ h16,
    float* __restrict__ s_src, float* __restrict__ s_dst)
{
    __shared__ float WL[64 * WSTRIDE];            // WL[c*66 + k] = W[c][k]
    __shared__ float xs[ROWS_PER_BLOCK * 64];
    const int tid  = threadIdx.x;
    const int lane = tid & 63;
    const int wv   = tid >> 6;

    for (int idx = tid * 4; idx < 64 * 64; idx += 256 * 4) {
        const float4 w = *(const float4*)(W + idx);
        const int c = idx >> 6, k = idx & 63;
        WL[c * WSTRIDE + k + 0] = w.x;
        WL[c * WSTRIDE + k + 1] = w.y;
        WL[c * WSTRIDE + k + 2] = w.z;
        WL[c * WSTRIDE + k + 3] = w.w;
    }
    const int row0 = blockIdx.x * ROWS_PER_BLOCK;
    for (int idx = tid * 4; idx < ROWS_PER_BLOCK * 64; idx += 256 * 4)
        *(float4*)(xs + idx) = *(const float4*)(x + (size_t)row0 * 64 + idx);
    __syncthreads();

    const float bias = b[lane];
    float acc[8];
    #pragma unroll
    for (int r = 0; r < 8; ++r) acc[r] = bias;

    const int rbase = wv * 8;
    const float* wrow = WL + lane * WSTRIDE;
    const float* xrow = xs + rbase * 64;
    #pragma unroll 1   // DO NOT unroll: keeps live set small (see header)
    for (int kk = 0; kk < 64; kk += 4) {
        const float2 w01 = *(const float2*)(wrow + kk);
        const float2 w23 = *(const float2*)(wrow + kk + 2);
        #pragma unroll
        for (int r = 0; r < 8; ++r) {
            const float4 xq = *(const float4*)(xrow + r * 64 + kk);
            acc[r] += xq.x * w01.x + xq.y * w01.y + xq.z * w23.x + xq.w * w23.y;
        }
    }

    const float asrc = a[(lane >> 3) * 16 + (lane & 7)];
    const float adst = a[(lane >> 3) * 16 + 8 + (lane & 7)];
    #pragma unroll
    for (int r = 0; r < 8; ++r) {
        const int row = row0 + rbase + r;
        const float v = acc[r];
        h16[(size_t)row * 64 + lane] = __float2half_rn(v);
        float p = v * asrc, q = v * adst;
        p += __shfl_xor(p, 1);  q += __shfl_xor(q, 1);
        p += __shfl_xor(p, 2);  q += __shfl_xor(q, 2);
        p += __shfl_xor(p, 4);  q += __shfl_xor(q, 4);
        if ((lane & 7) == 0) {
            s_src[row * 8 + (lane >> 3)] = p;
            s_dst[row * 8 + (lane >> 3)] = q;
        }
    }
}

// ---------------------------------------------------------------------------
// k_hist: bucket-level (src>>6) histogram.  LDS compresses 8192 edges/block
// into <=1563 sequential global atomics (294K total).
// ---------------------------------------------------------------------------
__global__ __launch_bounds__(1024) void k_hist(
    const int* __restrict__ ei, int* __restrict__ bhist)
{
    __shared__ int hist[NBKT];
    const int tid = threadIdx.x;
    for (int b = tid; b < NBKT; b += 1024) hist[b] = 0;
    __syncthreads();
    const int e0 = blockIdx.x * BIN_TILE;
    #pragma unroll
    for (int j = 0; j < 8; ++j) {
        const int e = e0 + j * 1024 + tid;
        if (e < N_EDGES) atomicAdd(&hist[ei[e] >> 6], 1);
    }
    __syncthreads();
    for (int b = tid; b < NBKT; b += 1024)
        if (hist[b]) atomicAdd(&bhist[b], hist[b]);
}

// ---------------------------------------------------------------------------
// k_bscan: exclusive scan of the 1563 bucket counts -> bucket_base (segment
// bounds for k_place) + gbin (scatter frontiers for k_bin).
// ---------------------------------------------------------------------------
__global__ __launch_bounds__(1024) void k_bscan(
    const int* __restrict__ bhist, int* __restrict__ bucket_base,
    int* __restrict__ gbin)
{
    __shared__ int wsum[16];
    const int tid = threadIdx.x, lane = tid & 63, wv = tid >> 6;

    int v = (tid < NBKT) ? bhist[tid] : 0;
    int sc = v;
    #pragma unroll
    for (int off = 1; off < 64; off <<= 1) {
        int t = __shfl_up(sc, off);
        if (lane >= off) sc += t;
    }
    if (lane == 63) wsum[wv] = sc;
    __syncthreads();
    if (tid < 16) {
        int ws = wsum[tid];
        #pragma unroll
        for (int off = 1; off < 16; off <<= 1) {
            int t = __shfl_up(ws, off);
            if (tid >= off) ws += t;
        }
        wsum[tid] = ws;
    }
    __syncthreads();
    const int pref0 = wv ? wsum[wv - 1] : 0;
    const int ex0 = pref0 + sc - v;
    if (tid < NBKT) { bucket_base[tid] = ex0; gbin[tid] = ex0; }
    const int T1 = wsum[15];
    __syncthreads();

    const int i2 = 1024 + tid;
    int v2 = (i2 < NBKT) ? bhist[i2] : 0;
    int sc2 = v2;
    #pragma unroll
    for (int off = 1; off < 64; off <<= 1) {
        int t = __shfl_up(sc2, off);
        if (lane >= off) sc2 += t;
    }
    if (lane == 63) wsum[wv] = sc2;
    __syncthreads();
    if (tid < 16) {
        int ws = wsum[tid];
        #pragma unroll
        for (int off = 1; off < 16; off <<= 1) {
            int t = __shfl_up(ws, off);
            if (tid >= off) ws += t;
        }
        wsum[tid] = ws;
    }
    __syncthreads();
    const int pref1 = wv ? wsum[wv - 1] : 0;
    const int ex1 = T1 + pref1 + sc2 - v2;
    if (i2 < NBKT) { bucket_base[i2] = ex1; gbin[i2] = ex1; }
    if (tid == 0) bucket_base[NBKT] = N_EDGES;
}

// ---------------------------------------------------------------------------
// k_bin: bucket edges by src>>6.  LDS histogram (atomic return = local
// rank), ONE global atomic per (block,bucket) claims a contiguous run, then
// each thread writes its packed word at base+rank.  word = (src&63) |
// (dst<<6) -- 4B/edge (src&63 == src-64g since bucket fixes src>>6).
// ---------------------------------------------------------------------------
__global__ __launch_bounds__(1024) void k_bin(
    const int* __restrict__ ei, int* __restrict__ gbin,
    unsigned int* __restrict__ staged)
{
    __shared__ int hist[NBKT];
    __shared__ int base[NBKT];
    const int tid = threadIdx.x;
    for (int b = tid; b < NBKT; b += 1024) hist[b] = 0;
    __syncthreads();

    int s[8], d[8], r[8];
    const int e0 = blockIdx.x * BIN_TILE;
    #pragma unroll
    for (int j = 0; j < 8; ++j) {
        const int e = e0 + j * 1024 + tid;
        if (e < N_EDGES) {
            s[j] = ei[e];
            d[j] = ei[N_EDGES + e];
            r[j] = atomicAdd(&hist[s[j] >> 6], 1);
        }
    }
    __syncthreads();
    for (int b = tid; b < NBKT; b += 1024)
        if (hist[b]) base[b] = atomicAdd(&gbin[b], hist[b]);
    __syncthreads();
    #pragma unroll
    for (int j = 0; j < 8; ++j) {
        const int e = e0 + j * 1024 + tid;
        if (e < N_EDGES)
            staged[(size_t)base[s[j] >> 6] + r[j]] =
                (unsigned int)((s[j] & 63) | (d[j] << 6));
    }
}

// ---------------------------------------------------------------------------
// k_place: block g owns nodes [g*64, g*64+64) and segment
// [bucket_base[g], bucket_base[g+1]).  Pass A: LDS histogram of the 64 node
// degrees + wave-scan -> row_ptr.  Pass B (segment re-read, L2-hot): alpha
// + slot via LDS cursors; R17 writes TWO flat streams (dst_sorted 4B,
// alpha16 16B) instead of interleaved rec -- both windows block-exclusive
// per the R14 invariant; gather gets immediate-offset addressing.
// ---------------------------------------------------------------------------
__global__ __launch_bounds__(1024) void k_place(
    const int* __restrict__ bucket_base, const unsigned int* __restrict__ staged,
    const float* __restrict__ s_src, const float* __restrict__ s_dst,
    int* __restrict__ row_ptr, int* __restrict__ dst_sorted,
    __half* __restrict__ alpha16)
{
    __shared__ int cnt[WB];
    __shared__ int cur[WB];
    const int g   = blockIdx.x;
    const int n0  = g * WB;
    const int tid = threadIdx.x;
    if (tid < WB) cnt[tid] = 0;
    __syncthreads();
    const int beg = bucket_base[g];
    const int end = bucket_base[g + 1];

    for (int j = beg + tid; j < end; j += 1024)
        atomicAdd(&cnt[staged[j] & 63u], 1);
    __syncthreads();
    if (tid < WB) {
        const int c = cnt[tid];
        int sc = c;
        #pragma unroll
        for (int off = 1; off < 64; off <<= 1) {
            int t = __shfl_up(sc, off);
            if (tid >= off) sc += t;
        }
        const int rp = beg + sc - c;     // global exclusive prefix
        cur[tid] = rp;
        if (n0 + tid < N_NODES) row_ptr[n0 + tid] = rp;
    }
    if (g == NBKT - 1 && tid == 0) row_ptr[N_NODES] = N_EDGES;
    __syncthreads();

    for (int j = beg + tid; j < end; j += 1024) {
        const unsigned int w = staged[j];
        const int srcl = (int)(w & 63u);
        const int dst  = (int)(w >> 6);

        const float4 a0 = *(const float4*)(s_src + (size_t)(n0 + srcl) * 8);
        const float4 a1 = *(const float4*)(s_src + (size_t)(n0 + srcl) * 8 + 4);
        const float4 b0 = *(const float4*)(s_dst + (size_t)dst * 8);
        const float4 b1 = *(const float4*)(s_dst + (size_t)dst * 8 + 4);
        float sc[8] = {a0.x + b0.x, a0.y + b0.y, a0.z + b0.z, a0.w + b0.w,
                       a1.x + b1.x, a1.y + b1.y, a1.z + b1.z, a1.w + b1.w};
        float m = -1e30f;
        #pragma unroll
        for (int h = 0; h < 8; ++h) {
            sc[h] = (sc[h] >= 0.f) ? sc[h] : 0.2f * sc[h];
            m = fmaxf(m, sc[h]);
        }
        float sum = 0.f;
        #pragma unroll
        for (int h = 0; h < 8; ++h) { sc[h] = __expf(sc[h] - m); sum += sc[h]; }
        const float inv = 1.f / sum;
        unsigned int q[4];
        #pragma unroll
        for (int jj = 0; jj < 4; ++jj) {
            const unsigned short lo = __half_as_ushort(__float2half_rn(sc[2*jj]   * inv));
            const unsigned short hi = __half_as_ushort(__float2half_rn(sc[2*jj+1] * inv));
            q[jj] = (unsigned int)lo | ((unsigned int)hi << 16);
        }

        const int slot = atomicAdd(&cur[srcl], 1);
        dst_sorted[slot] = dst;
        *(uint4*)(alpha16 + (size_t)slot * 8) = make_uint4(q[0], q[1], q[2], q[3]);
    }
}

// ---------------------------------------------------------------------------
// Gather + epilogue: one wave per node.  R17 instruction diet: two flat
// streams with base+immediate addressing, hoisted lane/head base pointers,
// 32-bit indices (max 12.8M), unroll 8 with all loads issued before use.
// ---------------------------------------------------------------------------
__global__ __launch_bounds__(256) void k_gather(
    const int* __restrict__ row_ptr, const int* __restrict__ dst_sorted,
    const __half* __restrict__ alpha16, const __half* __restrict__ h16,
    const float* __restrict__ x, const float* __restrict__ ln_scale,
    const float* __restrict__ ln_bias, float* __restrict__ out)
{
    const int i = blockIdx.x * 4 + (threadIdx.x >> 6);
    if (i >= N_NODES) return;
    const int lane = threadIdx.x & 63;
    const int head = lane >> 3;

    const int beg = row_ptr[i];
    const int end = row_ptr[i + 1];
    const float xres = x[(size_t)i * 64 + lane];

    const __half* __restrict__ hp = h16 + lane;      // row d -> hp[d*64]
    const __half* __restrict__ ap = alpha16 + head;  // edge e -> ap[e*8]

    float acc = 0.f;
    int e = beg;
    for (; e + 7 < end; e += 8) {
        int d[8];
        #pragma unroll
        for (int j = 0; j < 8; ++j) d[j] = dst_sorted[e + j];
        float al[8];
        #pragma unroll
        for (int j = 0; j < 8; ++j) al[j] = __half2float(ap[(e + j) * 8]);
        float hv[8];
        #pragma unroll
        for (int j = 0; j < 8; ++j) hv[j] = __half2float(hp[d[j] * 64]);
        #pragma unroll
        for (int j = 0; j < 8; ++j) acc = fmaf(al[j], hv[j], acc);
    }
    for (; e + 3 < end; e += 4) {
        int d[4];
        #pragma unroll
        for (int j = 0; j < 4; ++j) d[j] = dst_sorted[e + j];
        float al[4];
        #pragma unroll
        for (int j = 0; j < 4; ++j) al[j] = __half2float(ap[(e + j) * 8]);
        float hv[4];
        #pragma unroll
        for (int j = 0; j < 4; ++j) hv[j] = __half2float(hp[d[j] * 64]);
        #pragma unroll
        for (int j = 0; j < 4; ++j) acc = fmaf(al[j], hv[j], acc);
    }
    for (; e < end; ++e)
        acc = fmaf(__half2float(ap[e * 8]),
                   __half2float(hp[dst_sorted[e] * 64]), acc);

    // epilogue: residual + LayerNorm + L2 normalize
    float v = acc + xres;
    float s = v;
    #pragma unroll
    for (int off = 1; off < 64; off <<= 1) s += __shfl_xor(s, off);
    const float mu = s * (1.f / 64.f);
    const float d = v - mu;
    float vs = d * d;
    #pragma unroll
    for (int off = 1; off < 64; off <<= 1) vs += __shfl_xor(vs, off);
    const float var = vs * (1.f / 64.f);
    float y = d * rsqrtf(var + LN_EPS) * ln_scale[lane] + ln_bias[lane];
    float ss = y * y;
    #pragma unroll
    for (int off = 1; off < 64; off <<= 1) ss += __shfl_xor(ss, off);
    const float norm = sqrtf(ss);
    out[(size_t)i * 64 + lane] = y / fmaxf(norm, NORM_EPS);
}

// ---------------------------------------------------------------------------
extern "C" void kernel_launch(void* const* d_in, const int* in_sizes, int n_in,
                              void* d_out, int out_size, void* d_ws, size_t ws_size,
                              hipStream_t stream)
{
    const float* x        = (const float*)d_in[0];
    const int*   ei       = (const int*)d_in[1];
    const float* W        = (const float*)d_in[2];
    const float* b        = (const float*)d_in[3];
    const float* a        = (const float*)d_in[4];
    const float* ln_scale = (const float*)d_in[5];
    const float* ln_bias  = (const float*)d_in[6];
    float* out = (float*)d_out;

    char* ws = (char*)d_ws;
    size_t off = 0;
    auto alloc = [&](size_t bytes) {
        void* p = ws + off;
        off = (off + bytes + 255) & ~(size_t)255;
        return p;
    };
    __half* h16        = (__half*)alloc((size_t)N_NODES * 64 * 2);
    float*  s_src      = (float*) alloc((size_t)N_NODES * 8 * 4);
    float*  s_dst      = (float*) alloc((size_t)N_NODES * 8 * 4);
    int*    bhist      = (int*)   alloc((size_t)NBKT * 4);
    int*    bucket_base= (int*)   alloc((size_t)(NBKT + 1) * 4);
    int*    gbin       = (int*)   alloc((size_t)NBKT * 4);
    int*    row_ptr    = (int*)   alloc((size_t)(N_NODES + 1) * 4);
    unsigned int* staged = (unsigned int*)alloc((size_t)N_EDGES * 4);
    int*    dst_sorted = (int*)   alloc((size_t)N_EDGES * 4);
    __half* alpha16    = (__half*)alloc((size_t)N_EDGES * 8 * 2);

    hipMemsetAsync(bhist, 0, (size_t)NBKT * 4, stream);

    k_hist  <<<BIN_BLOCKS, 1024, 0, stream>>>(ei, bhist);
    k_bscan <<<1, 1024, 0, stream>>>(bhist, bucket_base, gbin);
    k_gemm  <<<GEMM_BLOCKS, 256, 0, stream>>>(x, W, b, a, h16, s_src, s_dst);
    k_bin   <<<BIN_BLOCKS, 1024, 0, stream>>>(ei, gbin, staged);
    k_place <<<NBKT, 1024, 0, stream>>>(bucket_base, staged, s_src, s_dst,
                                        row_ptr, dst_sorted, alpha16);
    k_gather<<<(N_NODES + 3) / 4, 256, 0, stream>>>(row_ptr, dst_sorted, alpha16,
                                                    h16, x, ln_scale, ln_bias, out);
}

// Round 8
// 231.756 us; speedup vs baseline: 3.3786x; 1.0127x over previous
//
#include <hip/hip_runtime.h>
#include <hip/hip_fp16.h>
#include <math.h>

#define N_NODES 100000
#define N_EDGES 1600000
#define LN_EPS 1e-5f
#define NORM_EPS 1e-12f
#define ROWS_PER_BLOCK 32
#define GEMM_BLOCKS (N_NODES / ROWS_PER_BLOCK)            // 3125, exact
#define WSTRIDE 66   // even (b64-aligned) and 2c+k -> 2-way banks (free)
// R12/R13 ERRATA (measured): scattered partial-line stores pay a full 64B
// fetch+WB PER TOUCH whenever consecutive records of a line are written by
// different workgroups.  Invariant: coalescing happens ONLY when one block
// (one CU/L2) owns all writes to a line.  R14 (WIN 317->292): bucketed
// counting sort.  R15 (WIN 292->254): bucket-level histogram replaced the
// 1.6M random node atomics (+49.4MB WRITE / ~50us in gemm).
// R16 ERRATA (FAILED 254->783): fusing gather into k_place serialized on
// ONE h16 load in flight per wave (VALU 6%, HBM 3%).  Gather needs the
// unrolled many-loads-in-flight, barrier-free wave structure.  REVERTED.
// R17 (WIN 254->235): flat dst_sorted[]+alpha16[] streams, hoisted bases,
// 32-bit indices, unroll 8 -- gather 77->65us, now VALU-ISSUE-bound
// (VALUBusy 61%, HBM 27%).
// R18: half2 feature packing -- lane covers 2 features (one 4B half2 load),
// freed wave-half processes a 2nd edge concurrently (even/odd split, one
// shfl_xor(32) combine).  ~2x fewer wave-instructions AND loads per edge;
// epilogue reductions 6->5 shfl steps; float2 stores.
#define WB 64                                   // nodes per place-bucket
#define NBKT ((N_NODES + WB - 1) / WB)          // 1563
#define BIN_TILE 8192                           // 1024 thr x 8 edges
#define BIN_BLOCKS ((N_EDGES + BIN_TILE - 1) / BIN_TILE)  // 196

// ---------------------------------------------------------------------------
// K1: h = x @ W^T + b (N x 64) -> fp16 (|h|~6 << 65504; 8x less quant error
// than bf16); per-node attn scores fp32.  PURE GEMM (R15).  K-LOOP
// DELIBERATELY NOT UNROLLED (#pragma unroll 1): R5/R6 measured the unrolled
// version spilling acc[] at ANY VGPR budget.  No min-waves hint (R5).  NO
// nontemporal hints (R9).  NO cooperative launch (R10: grid.sync ~200us).
// ---------------------------------------------------------------------------
__global__ __launch_bounds__(256) void k_gemm(
    const float* __restrict__ x, const float* __restrict__ W,
    const float* __restrict__ b, const float* __restrict__ a,
    __half* __restrict__ h16,
    float* __restrict__ s_src, float* __restrict__ s_dst)
{
    __shared__ float WL[64 * WSTRIDE];            // WL[c*66 + k] = W[c][k]
    __shared__ float xs[ROWS_PER_BLOCK * 64];
    const int tid  = threadIdx.x;
    const int lane = tid & 63;
    const int wv   = tid >> 6;

    for (int idx = tid * 4; idx < 64 * 64; idx += 256 * 4) {
        const float4 w = *(const float4*)(W + idx);
        const int c = idx >> 6, k = idx & 63;
        WL[c * WSTRIDE + k + 0] = w.x;
        WL[c * WSTRIDE + k + 1] = w.y;
        WL[c * WSTRIDE + k + 2] = w.z;
        WL[c * WSTRIDE + k + 3] = w.w;
    }
    const int row0 = blockIdx.x * ROWS_PER_BLOCK;
    for (int idx = tid * 4; idx < ROWS_PER_BLOCK * 64; idx += 256 * 4)
        *(float4*)(xs + idx) = *(const float4*)(x + (size_t)row0 * 64 + idx);
    __syncthreads();

    const float bias = b[lane];
    float acc[8];
    #pragma unroll
    for (int r = 0; r < 8; ++r) acc[r] = bias;

    const int rbase = wv * 8;
    const float* wrow = WL + lane * WSTRIDE;
    const float* xrow = xs + rbase * 64;
    #pragma unroll 1   // DO NOT unroll: keeps live set small (see header)
    for (int kk = 0; kk < 64; kk += 4) {
        const float2 w01 = *(const float2*)(wrow + kk);
        const float2 w23 = *(const float2*)(wrow + kk + 2);
        #pragma unroll
        for (int r = 0; r < 8; ++r) {
            const float4 xq = *(const float4*)(xrow + r * 64 + kk);
            acc[r] += xq.x * w01.x + xq.y * w01.y + xq.z * w23.x + xq.w * w23.y;
        }
    }

    const float asrc = a[(lane >> 3) * 16 + (lane & 7)];
    const float adst = a[(lane >> 3) * 16 + 8 + (lane & 7)];
    #pragma unroll
    for (int r = 0; r < 8; ++r) {
        const int row = row0 + rbase + r;
        const float v = acc[r];
        h16[(size_t)row * 64 + lane] = __float2half_rn(v);
        float p = v * asrc, q = v * adst;
        p += __shfl_xor(p, 1);  q += __shfl_xor(q, 1);
        p += __shfl_xor(p, 2);  q += __shfl_xor(q, 2);
        p += __shfl_xor(p, 4);  q += __shfl_xor(q, 4);
        if ((lane & 7) == 0) {
            s_src[row * 8 + (lane >> 3)] = p;
            s_dst[row * 8 + (lane >> 3)] = q;
        }
    }
}

// ---------------------------------------------------------------------------
// k_hist: bucket-level (src>>6) histogram.  LDS compresses 8192 edges/block
// into <=1563 sequential global atomics (294K total).
// ---------------------------------------------------------------------------
__global__ __launch_bounds__(1024) void k_hist(
    const int* __restrict__ ei, int* __restrict__ bhist)
{
    __shared__ int hist[NBKT];
    const int tid = threadIdx.x;
    for (int b = tid; b < NBKT; b += 1024) hist[b] = 0;
    __syncthreads();
    const int e0 = blockIdx.x * BIN_TILE;
    #pragma unroll
    for (int j = 0; j < 8; ++j) {
        const int e = e0 + j * 1024 + tid;
        if (e < N_EDGES) atomicAdd(&hist[ei[e] >> 6], 1);
    }
    __syncthreads();
    for (int b = tid; b < NBKT; b += 1024)
        if (hist[b]) atomicAdd(&bhist[b], hist[b]);
}

// ---------------------------------------------------------------------------
// k_bscan: exclusive scan of the 1563 bucket counts -> bucket_base (segment
// bounds for k_place) + gbin (scatter frontiers for k_bin).
// ---------------------------------------------------------------------------
__global__ __launch_bounds__(1024) void k_bscan(
    const int* __restrict__ bhist, int* __restrict__ bucket_base,
    int* __restrict__ gbin)
{
    __shared__ int wsum[16];
    const int tid = threadIdx.x, lane = tid & 63, wv = tid >> 6;

    int v = (tid < NBKT) ? bhist[tid] : 0;
    int sc = v;
    #pragma unroll
    for (int off = 1; off < 64; off <<= 1) {
        int t = __shfl_up(sc, off);
        if (lane >= off) sc += t;
    }
    if (lane == 63) wsum[wv] = sc;
    __syncthreads();
    if (tid < 16) {
        int ws = wsum[tid];
        #pragma unroll
        for (int off = 1; off < 16; off <<= 1) {
            int t = __shfl_up(ws, off);
            if (tid >= off) ws += t;
        }
        wsum[tid] = ws;
    }
    __syncthreads();
    const int pref0 = wv ? wsum[wv - 1] : 0;
    const int ex0 = pref0 + sc - v;
    if (tid < NBKT) { bucket_base[tid] = ex0; gbin[tid] = ex0; }
    const int T1 = wsum[15];
    __syncthreads();

    const int i2 = 1024 + tid;
    int v2 = (i2 < NBKT) ? bhist[i2] : 0;
    int sc2 = v2;
    #pragma unroll
    for (int off = 1; off < 64; off <<= 1) {
        int t = __shfl_up(sc2, off);
        if (lane >= off) sc2 += t;
    }
    if (lane == 63) wsum[wv] = sc2;
    __syncthreads();
    if (tid < 16) {
        int ws = wsum[tid];
        #pragma unroll
        for (int off = 1; off < 16; off <<= 1) {
            int t = __shfl_up(ws, off);
            if (tid >= off) ws += t;
        }
        wsum[tid] = ws;
    }
    __syncthreads();
    const int pref1 = wv ? wsum[wv - 1] : 0;
    const int ex1 = T1 + pref1 + sc2 - v2;
    if (i2 < NBKT) { bucket_base[i2] = ex1; gbin[i2] = ex1; }
    if (tid == 0) bucket_base[NBKT] = N_EDGES;
}

// ---------------------------------------------------------------------------
// k_bin: bucket edges by src>>6.  LDS histogram (atomic return = local
// rank), ONE global atomic per (block,bucket) claims a contiguous run, then
// each thread writes its packed word at base+rank.  word = (src&63) |
// (dst<<6) -- 4B/edge (src&63 == src-64g since bucket fixes src>>6).
// ---------------------------------------------------------------------------
__global__ __launch_bounds__(1024) void k_bin(
    const int* __restrict__ ei, int* __restrict__ gbin,
    unsigned int* __restrict__ staged)
{
    __shared__ int hist[NBKT];
    __shared__ int base[NBKT];
    const int tid = threadIdx.x;
    for (int b = tid; b < NBKT; b += 1024) hist[b] = 0;
    __syncthreads();

    int s[8], d[8], r[8];
    const int e0 = blockIdx.x * BIN_TILE;
    #pragma unroll
    for (int j = 0; j < 8; ++j) {
        const int e = e0 + j * 1024 + tid;
        if (e < N_EDGES) {
            s[j] = ei[e];
            d[j] = ei[N_EDGES + e];
            r[j] = atomicAdd(&hist[s[j] >> 6], 1);
        }
    }
    __syncthreads();
    for (int b = tid; b < NBKT; b += 1024)
        if (hist[b]) base[b] = atomicAdd(&gbin[b], hist[b]);
    __syncthreads();
    #pragma unroll
    for (int j = 0; j < 8; ++j) {
        const int e = e0 + j * 1024 + tid;
        if (e < N_EDGES)
            staged[(size_t)base[s[j] >> 6] + r[j]] =
                (unsigned int)((s[j] & 63) | (d[j] << 6));
    }
}

// ---------------------------------------------------------------------------
// k_place: block g owns nodes [g*64, g*64+64) and segment
// [bucket_base[g], bucket_base[g+1]).  Pass A: LDS histogram of the 64 node
// degrees + wave-scan -> row_ptr.  Pass B (segment re-read, L2-hot): alpha
// + slot via LDS cursors; writes TWO flat streams (dst_sorted 4B, alpha16
// 16B) -- both windows block-exclusive per the R14 invariant.
// ---------------------------------------------------------------------------
__global__ __launch_bounds__(1024) void k_place(
    const int* __restrict__ bucket_base, const unsigned int* __restrict__ staged,
    const float* __restrict__ s_src, const float* __restrict__ s_dst,
    int* __restrict__ row_ptr, int* __restrict__ dst_sorted,
    __half* __restrict__ alpha16)
{
    __shared__ int cnt[WB];
    __shared__ int cur[WB];
    const int g   = blockIdx.x;
    const int n0  = g * WB;
    const int tid = threadIdx.x;
    if (tid < WB) cnt[tid] = 0;
    __syncthreads();
    const int beg = bucket_base[g];
    const int end = bucket_base[g + 1];

    for (int j = beg + tid; j < end; j += 1024)
        atomicAdd(&cnt[staged[j] & 63u], 1);
    __syncthreads();
    if (tid < WB) {
        const int c = cnt[tid];
        int sc = c;
        #pragma unroll
        for (int off = 1; off < 64; off <<= 1) {
            int t = __shfl_up(sc, off);
            if (tid >= off) sc += t;
        }
        const int rp = beg + sc - c;     // global exclusive prefix
        cur[tid] = rp;
        if (n0 + tid < N_NODES) row_ptr[n0 + tid] = rp;
    }
    if (g == NBKT - 1 && tid == 0) row_ptr[N_NODES] = N_EDGES;
    __syncthreads();

    for (int j = beg + tid; j < end; j += 1024) {
        const unsigned int w = staged[j];
        const int srcl = (int)(w & 63u);
        const int dst  = (int)(w >> 6);

        const float4 a0 = *(const float4*)(s_src + (size_t)(n0 + srcl) * 8);
        const float4 a1 = *(const float4*)(s_src + (size_t)(n0 + srcl) * 8 + 4);
        const float4 b0 = *(const float4*)(s_dst + (size_t)dst * 8);
        const float4 b1 = *(const float4*)(s_dst + (size_t)dst * 8 + 4);
        float sc[8] = {a0.x + b0.x, a0.y + b0.y, a0.z + b0.z, a0.w + b0.w,
                       a1.x + b1.x, a1.y + b1.y, a1.z + b1.z, a1.w + b1.w};
        float m = -1e30f;
        #pragma unroll
        for (int h = 0; h < 8; ++h) {
            sc[h] = (sc[h] >= 0.f) ? sc[h] : 0.2f * sc[h];
            m = fmaxf(m, sc[h]);
        }
        float sum = 0.f;
        #pragma unroll
        for (int h = 0; h < 8; ++h) { sc[h] = __expf(sc[h] - m); sum += sc[h]; }
        const float inv = 1.f / sum;
        unsigned int q[4];
        #pragma unroll
        for (int jj = 0; jj < 4; ++jj) {
            const unsigned short lo = __half_as_ushort(__float2half_rn(sc[2*jj]   * inv));
            const unsigned short hi = __half_as_ushort(__float2half_rn(sc[2*jj+1] * inv));
            q[jj] = (unsigned int)lo | ((unsigned int)hi << 16);
        }

        const int slot = atomicAdd(&cur[srcl], 1);
        dst_sorted[slot] = dst;
        *(uint4*)(alpha16 + (size_t)slot * 8) = make_uint4(q[0], q[1], q[2], q[3]);
    }
}

// ---------------------------------------------------------------------------
// Gather + epilogue (R18): one wave per node, half2 feature packing.
// Lane l covers features {2*(l&31), 2*(l&31)+1} (same head: head=f>>3);
// lanes 0-31 process even edges, 32-63 odd edges concurrently.  Per 2 edges
// the wave issues ~half of R17's instructions and loads.  Partials combine
// via one shfl_xor(32); then 32 lanes hold all 64 features (both halves
// duplicated) -> 5-step epilogue reductions, float2 store from sub==0.
// ---------------------------------------------------------------------------
__global__ __launch_bounds__(256) void k_gather(
    const int* __restrict__ row_ptr, const int* __restrict__ dst_sorted,
    const __half* __restrict__ alpha16, const __half* __restrict__ h16,
    const float* __restrict__ x, const float* __restrict__ ln_scale,
    const float* __restrict__ ln_bias, float* __restrict__ out)
{
    const int i = blockIdx.x * 4 + (threadIdx.x >> 6);
    if (i >= N_NODES) return;
    const int lane = threadIdx.x & 63;
    const int fl   = lane & 31;        // feature-pair index: features 2fl, 2fl+1
    const int sub  = lane >> 5;        // 0: even edges, 1: odd edges
    const int hidx = fl >> 2;          // head of features 2fl,2fl+1

    const int beg = row_ptr[i];
    const int end = row_ptr[i + 1];

    const float2 xr = *(const float2*)(x + (size_t)i * 64 + 2 * fl);
    const __half* __restrict__ ap = alpha16 + hidx;              // edge e -> ap[e*8]
    const unsigned int* __restrict__ hp =
        (const unsigned int*)h16;                                 // row d, pair fl -> hp[d*32+fl]

    float acc0 = 0.f, acc1 = 0.f;
    int e = beg + sub;
    for (; e + 6 < end; e += 8) {                // 4 pairs -> 8 edges/wave-iter
        int d[4]; float al[4]; unsigned int h2[4];
        #pragma unroll
        for (int j = 0; j < 4; ++j) d[j] = dst_sorted[e + 2 * j];
        #pragma unroll
        for (int j = 0; j < 4; ++j) al[j] = __half2float(ap[(e + 2 * j) * 8]);
        #pragma unroll
        for (int j = 0; j < 4; ++j) h2[j] = hp[(size_t)d[j] * 32 + fl];
        #pragma unroll
        for (int j = 0; j < 4; ++j) {
            const float2 hf = __half22float2(*(const __half2*)&h2[j]);
            acc0 = fmaf(al[j], hf.x, acc0);
            acc1 = fmaf(al[j], hf.y, acc1);
        }
    }
    for (; e < end; e += 2) {
        const int d = dst_sorted[e];
        const float al = __half2float(ap[e * 8]);
        const unsigned int h2 = hp[(size_t)d * 32 + fl];
        const float2 hf = __half22float2(*(const __half2*)&h2);
        acc0 = fmaf(al, hf.x, acc0);
        acc1 = fmaf(al, hf.y, acc1);
    }
    // combine even/odd partials (both halves end with the full sums)
    acc0 += __shfl_xor(acc0, 32);
    acc1 += __shfl_xor(acc1, 32);

    // epilogue: residual + LayerNorm + L2 normalize over fl (32-lane butterflies)
    const float v0 = acc0 + xr.x;
    const float v1 = acc1 + xr.y;
    float s = v0 + v1;
    #pragma unroll
    for (int off = 1; off < 32; off <<= 1) s += __shfl_xor(s, off);
    const float mu = s * (1.f / 64.f);
    const float d0 = v0 - mu, d1 = v1 - mu;
    float vs = d0 * d0 + d1 * d1;
    #pragma unroll
    for (int off = 1; off < 32; off <<= 1) vs += __shfl_xor(vs, off);
    const float rstd = rsqrtf(vs * (1.f / 64.f) + LN_EPS);
    const float2 lsc = *(const float2*)(ln_scale + 2 * fl);
    const float2 lbi = *(const float2*)(ln_bias + 2 * fl);
    const float y0 = d0 * rstd * lsc.x + lbi.x;
    const float y1 = d1 * rstd * lsc.y + lbi.y;
    float ss = y0 * y0 + y1 * y1;
    #pragma unroll
    for (int off = 1; off < 32; off <<= 1) ss += __shfl_xor(ss, off);
    const float inv_norm = 1.f / fmaxf(sqrtf(ss), NORM_EPS);
    if (sub == 0)
        *(float2*)(out + (size_t)i * 64 + 2 * fl) =
            make_float2(y0 * inv_norm, y1 * inv_norm);
}

// ---------------------------------------------------------------------------
extern "C" void kernel_launch(void* const* d_in, const int* in_sizes, int n_in,
                              void* d_out, int out_size, void* d_ws, size_t ws_size,
                              hipStream_t stream)
{
    const float* x        = (const float*)d_in[0];
    const int*   ei       = (const int*)d_in[1];
    const float* W        = (const float*)d_in[2];
    const float* b        = (const float*)d_in[3];
    const float* a        = (const float*)d_in[4];
    const float* ln_scale = (const float*)d_in[5];
    const float* ln_bias  = (const float*)d_in[6];
    float* out = (float*)d_out;

    char* ws = (char*)d_ws;
    size_t off = 0;
    auto alloc = [&](size_t bytes) {
        void* p = ws + off;
        off = (off + bytes + 255) & ~(size_t)255;
        return p;
    };
    __half* h16        = (__half*)alloc((size_t)N_NODES * 64 * 2);
    float*  s_src      = (float*) alloc((size_t)N_NODES * 8 * 4);
    float*  s_dst      = (float*) alloc((size_t)N_NODES * 8 * 4);
    int*    bhist      = (int*)   alloc((size_t)NBKT * 4);
    int*    bucket_base= (int*)   alloc((size_t)(NBKT + 1) * 4);
    int*    gbin       = (int*)   alloc((size_t)NBKT * 4);
    int*    row_ptr    = (int*)   alloc((size_t)(N_NODES + 1) * 4);
    unsigned int* staged = (unsigned int*)alloc((size_t)N_EDGES * 4);
    int*    dst_sorted = (int*)   alloc((size_t)N_EDGES * 4);
    __half* alpha16    = (__half*)alloc((size_t)N_EDGES * 8 * 2);

    hipMemsetAsync(bhist, 0, (size_t)NBKT * 4, stream);

    k_hist  <<<BIN_BLOCKS, 1024, 0, stream>>>(ei, bhist);
    k_bscan <<<1, 1024, 0, stream>>>(bhist, bucket_base, gbin);
    k_gemm  <<<GEMM_BLOCKS, 256, 0, stream>>>(x, W, b, a, h16, s_src, s_dst);
    k_bin   <<<BIN_BLOCKS, 1024, 0, stream>>>(ei, gbin, staged);
    k_place <<<NBKT, 1024, 0, stream>>>(bucket_base, staged, s_src, s_dst,
                                        row_ptr, dst_sorted, alpha16);
    k_gather<<<(N_NODES + 3) / 4, 256, 0, stream>>>(row_ptr, dst_sorted, alpha16,
                                                    h16, x, ln_scale, ln_bias, out);
}

// Round 9
// 226.436 us; speedup vs baseline: 3.4580x; 1.0235x over previous
//
#include <hip/hip_runtime.h>
#include <hip/hip_fp16.h>
#include <math.h>

#define N_NODES 100000
#define N_EDGES 1600000
#define LN_EPS 1e-5f
#define NORM_EPS 1e-12f
#define ROWS_PER_BLOCK 32
#define GEMM_BLOCKS (N_NODES / ROWS_PER_BLOCK)            // 3125, exact
#define WSTRIDE 66   // even (b64-aligned) and 2c+k -> 2-way banks (free)
// R12/R13 ERRATA (measured): scattered partial-line stores pay a full 64B
// fetch+WB PER TOUCH whenever consecutive records of a line are written by
// different workgroups.  Invariant: coalescing happens ONLY when one block
// (one CU/L2) owns all writes to a line.  R14 (WIN 317->292): bucketed
// counting sort.  R15 (WIN 292->254): bucket-level histogram replaced the
// 1.6M random node atomics (+49.4MB WRITE / ~50us in gemm).
// R16 ERRATA (FAILED 254->783): fusing gather into k_place serialized on
// ONE h16 load in flight per wave.  Gather needs unrolled many-loads-in-
// flight, barrier-free waves.  REVERTED.
// R17 (WIN 254->235): flat streams + 32-bit indices, gather 77->65us.
// R18 (neutral-ish 235->232): half2 packing halved lane-work but VALUBusy
// stayed 57% -> the VALU cost is per-lane 64-bit ADDRESS MATH, not cvt/fma;
// the even/odd e-split also made e divergent, blocking scalarization.
// R19: wave-uniform addressing.  readfirstlane(i) puts i/beg/end/e/dst in
// SGPRs: row_ptr+dst_sorted become s_load, h16/alpha16 loads become
// saddr-form (SGPR base + const voffset) -> ~3 VALU/edge (2 cvt + 1 fma).
#define WB 64                                   // nodes per place-bucket
#define NBKT ((N_NODES + WB - 1) / WB)          // 1563
#define BIN_TILE 8192                           // 1024 thr x 8 edges
#define BIN_BLOCKS ((N_EDGES + BIN_TILE - 1) / BIN_TILE)  // 196

// ---------------------------------------------------------------------------
// K1: h = x @ W^T + b (N x 64) -> fp16 (|h|~6 << 65504; 8x less quant error
// than bf16); per-node attn scores fp32.  PURE GEMM (R15).  K-LOOP
// DELIBERATELY NOT UNROLLED (#pragma unroll 1): R5/R6 measured the unrolled
// version spilling acc[] at ANY VGPR budget.  No min-waves hint (R5).  NO
// nontemporal hints (R9).  NO cooperative launch (R10: grid.sync ~200us).
// ---------------------------------------------------------------------------
__global__ __launch_bounds__(256) void k_gemm(
    const float* __restrict__ x, const float* __restrict__ W,
    const float* __restrict__ b, const float* __restrict__ a,
    __half* __restrict__ h16,
    float* __restrict__ s_src, float* __restrict__ s_dst)
{
    __shared__ float WL[64 * WSTRIDE];            // WL[c*66 + k] = W[c][k]
    __shared__ float xs[ROWS_PER_BLOCK * 64];
    const int tid  = threadIdx.x;
    const int lane = tid & 63;
    const int wv   = tid >> 6;

    for (int idx = tid * 4; idx < 64 * 64; idx += 256 * 4) {
        const float4 w = *(const float4*)(W + idx);
        const int c = idx >> 6, k = idx & 63;
        WL[c * WSTRIDE + k + 0] = w.x;
        WL[c * WSTRIDE + k + 1] = w.y;
        WL[c * WSTRIDE + k + 2] = w.z;
        WL[c * WSTRIDE + k + 3] = w.w;
    }
    const int row0 = blockIdx.x * ROWS_PER_BLOCK;
    for (int idx = tid * 4; idx < ROWS_PER_BLOCK * 64; idx += 256 * 4)
        *(float4*)(xs + idx) = *(const float4*)(x + (size_t)row0 * 64 + idx);
    __syncthreads();

    const float bias = b[lane];
    float acc[8];
    #pragma unroll
    for (int r = 0; r < 8; ++r) acc[r] = bias;

    const int rbase = wv * 8;
    const float* wrow = WL + lane * WSTRIDE;
    const float* xrow = xs + rbase * 64;
    #pragma unroll 1   // DO NOT unroll: keeps live set small (see header)
    for (int kk = 0; kk < 64; kk += 4) {
        const float2 w01 = *(const float2*)(wrow + kk);
        const float2 w23 = *(const float2*)(wrow + kk + 2);
        #pragma unroll
        for (int r = 0; r < 8; ++r) {
            const float4 xq = *(const float4*)(xrow + r * 64 + kk);
            acc[r] += xq.x * w01.x + xq.y * w01.y + xq.z * w23.x + xq.w * w23.y;
        }
    }

    const float asrc = a[(lane >> 3) * 16 + (lane & 7)];
    const float adst = a[(lane >> 3) * 16 + 8 + (lane & 7)];
    #pragma unroll
    for (int r = 0; r < 8; ++r) {
        const int row = row0 + rbase + r;
        const float v = acc[r];
        h16[(size_t)row * 64 + lane] = __float2half_rn(v);
        float p = v * asrc, q = v * adst;
        p += __shfl_xor(p, 1);  q += __shfl_xor(q, 1);
        p += __shfl_xor(p, 2);  q += __shfl_xor(q, 2);
        p += __shfl_xor(p, 4);  q += __shfl_xor(q, 4);
        if ((lane & 7) == 0) {
            s_src[row * 8 + (lane >> 3)] = p;
            s_dst[row * 8 + (lane >> 3)] = q;
        }
    }
}

// ---------------------------------------------------------------------------
// k_hist: bucket-level (src>>6) histogram.  LDS compresses 8192 edges/block
// into <=1563 sequential global atomics (294K total).
// ---------------------------------------------------------------------------
__global__ __launch_bounds__(1024) void k_hist(
    const int* __restrict__ ei, int* __restrict__ bhist)
{
    __shared__ int hist[NBKT];
    const int tid = threadIdx.x;
    for (int b = tid; b < NBKT; b += 1024) hist[b] = 0;
    __syncthreads();
    const int e0 = blockIdx.x * BIN_TILE;
    #pragma unroll
    for (int j = 0; j < 8; ++j) {
        const int e = e0 + j * 1024 + tid;
        if (e < N_EDGES) atomicAdd(&hist[ei[e] >> 6], 1);
    }
    __syncthreads();
    for (int b = tid; b < NBKT; b += 1024)
        if (hist[b]) atomicAdd(&bhist[b], hist[b]);
}

// ---------------------------------------------------------------------------
// k_bscan: exclusive scan of the 1563 bucket counts -> bucket_base (segment
// bounds for k_place) + gbin (scatter frontiers for k_bin).
// ---------------------------------------------------------------------------
__global__ __launch_bounds__(1024) void k_bscan(
    const int* __restrict__ bhist, int* __restrict__ bucket_base,
    int* __restrict__ gbin)
{
    __shared__ int wsum[16];
    const int tid = threadIdx.x, lane = tid & 63, wv = tid >> 6;

    int v = (tid < NBKT) ? bhist[tid] : 0;
    int sc = v;
    #pragma unroll
    for (int off = 1; off < 64; off <<= 1) {
        int t = __shfl_up(sc, off);
        if (lane >= off) sc += t;
    }
    if (lane == 63) wsum[wv] = sc;
    __syncthreads();
    if (tid < 16) {
        int ws = wsum[tid];
        #pragma unroll
        for (int off = 1; off < 16; off <<= 1) {
            int t = __shfl_up(ws, off);
            if (tid >= off) ws += t;
        }
        wsum[tid] = ws;
    }
    __syncthreads();
    const int pref0 = wv ? wsum[wv - 1] : 0;
    const int ex0 = pref0 + sc - v;
    if (tid < NBKT) { bucket_base[tid] = ex0; gbin[tid] = ex0; }
    const int T1 = wsum[15];
    __syncthreads();

    const int i2 = 1024 + tid;
    int v2 = (i2 < NBKT) ? bhist[i2] : 0;
    int sc2 = v2;
    #pragma unroll
    for (int off = 1; off < 64; off <<= 1) {
        int t = __shfl_up(sc2, off);
        if (lane >= off) sc2 += t;
    }
    if (lane == 63) wsum[wv] = sc2;
    __syncthreads();
    if (tid < 16) {
        int ws = wsum[tid];
        #pragma unroll
        for (int off = 1; off < 16; off <<= 1) {
            int t = __shfl_up(ws, off);
            if (tid >= off) ws += t;
        }
        wsum[tid] = ws;
    }
    __syncthreads();
    const int pref1 = wv ? wsum[wv - 1] : 0;
    const int ex1 = T1 + pref1 + sc2 - v2;
    if (i2 < NBKT) { bucket_base[i2] = ex1; gbin[i2] = ex1; }
    if (tid == 0) bucket_base[NBKT] = N_EDGES;
}

// ---------------------------------------------------------------------------
// k_bin: bucket edges by src>>6.  LDS histogram (atomic return = local
// rank), ONE global atomic per (block,bucket) claims a contiguous run, then
// each thread writes its packed word at base+rank.  word = (src&63) |
// (dst<<6) -- 4B/edge (src&63 == src-64g since bucket fixes src>>6).
// ---------------------------------------------------------------------------
__global__ __launch_bounds__(1024) void k_bin(
    const int* __restrict__ ei, int* __restrict__ gbin,
    unsigned int* __restrict__ staged)
{
    __shared__ int hist[NBKT];
    __shared__ int base[NBKT];
    const int tid = threadIdx.x;
    for (int b = tid; b < NBKT; b += 1024) hist[b] = 0;
    __syncthreads();

    int s[8], d[8], r[8];
    const int e0 = blockIdx.x * BIN_TILE;
    #pragma unroll
    for (int j = 0; j < 8; ++j) {
        const int e = e0 + j * 1024 + tid;
        if (e < N_EDGES) {
            s[j] = ei[e];
            d[j] = ei[N_EDGES + e];
            r[j] = atomicAdd(&hist[s[j] >> 6], 1);
        }
    }
    __syncthreads();
    for (int b = tid; b < NBKT; b += 1024)
        if (hist[b]) base[b] = atomicAdd(&gbin[b], hist[b]);
    __syncthreads();
    #pragma unroll
    for (int j = 0; j < 8; ++j) {
        const int e = e0 + j * 1024 + tid;
        if (e < N_EDGES)
            staged[(size_t)base[s[j] >> 6] + r[j]] =
                (unsigned int)((s[j] & 63) | (d[j] << 6));
    }
}

// ---------------------------------------------------------------------------
// k_place: block g owns nodes [g*64, g*64+64) and segment
// [bucket_base[g], bucket_base[g+1]).  Pass A: LDS histogram of the 64 node
// degrees + wave-scan -> row_ptr.  Pass B (segment re-read, L2-hot): alpha
// + slot via LDS cursors; writes TWO flat streams (dst_sorted 4B, alpha16
// 16B) -- both windows block-exclusive per the R14 invariant.
// ---------------------------------------------------------------------------
__global__ __launch_bounds__(1024) void k_place(
    const int* __restrict__ bucket_base, const unsigned int* __restrict__ staged,
    const float* __restrict__ s_src, const float* __restrict__ s_dst,
    int* __restrict__ row_ptr, int* __restrict__ dst_sorted,
    __half* __restrict__ alpha16)
{
    __shared__ int cnt[WB];
    __shared__ int cur[WB];
    const int g   = blockIdx.x;
    const int n0  = g * WB;
    const int tid = threadIdx.x;
    if (tid < WB) cnt[tid] = 0;
    __syncthreads();
    const int beg = bucket_base[g];
    const int end = bucket_base[g + 1];

    for (int j = beg + tid; j < end; j += 1024)
        atomicAdd(&cnt[staged[j] & 63u], 1);
    __syncthreads();
    if (tid < WB) {
        const int c = cnt[tid];
        int sc = c;
        #pragma unroll
        for (int off = 1; off < 64; off <<= 1) {
            int t = __shfl_up(sc, off);
            if (tid >= off) sc += t;
        }
        const int rp = beg + sc - c;     // global exclusive prefix
        cur[tid] = rp;
        if (n0 + tid < N_NODES) row_ptr[n0 + tid] = rp;
    }
    if (g == NBKT - 1 && tid == 0) row_ptr[N_NODES] = N_EDGES;
    __syncthreads();

    for (int j = beg + tid; j < end; j += 1024) {
        const unsigned int w = staged[j];
        const int srcl = (int)(w & 63u);
        const int dst  = (int)(w >> 6);

        const float4 a0 = *(const float4*)(s_src + (size_t)(n0 + srcl) * 8);
        const float4 a1 = *(const float4*)(s_src + (size_t)(n0 + srcl) * 8 + 4);
        const float4 b0 = *(const float4*)(s_dst + (size_t)dst * 8);
        const float4 b1 = *(const float4*)(s_dst + (size_t)dst * 8 + 4);
        float sc[8] = {a0.x + b0.x, a0.y + b0.y, a0.z + b0.z, a0.w + b0.w,
                       a1.x + b1.x, a1.y + b1.y, a1.z + b1.z, a1.w + b1.w};
        float m = -1e30f;
        #pragma unroll
        for (int h = 0; h < 8; ++h) {
            sc[h] = (sc[h] >= 0.f) ? sc[h] : 0.2f * sc[h];
            m = fmaxf(m, sc[h]);
        }
        float sum = 0.f;
        #pragma unroll
        for (int h = 0; h < 8; ++h) { sc[h] = __expf(sc[h] - m); sum += sc[h]; }
        const float inv = 1.f / sum;
        unsigned int q[4];
        #pragma unroll
        for (int jj = 0; jj < 4; ++jj) {
            const unsigned short lo = __half_as_ushort(__float2half_rn(sc[2*jj]   * inv));
            const unsigned short hi = __half_as_ushort(__float2half_rn(sc[2*jj+1] * inv));
            q[jj] = (unsigned int)lo | ((unsigned int)hi << 16);
        }

        const int slot = atomicAdd(&cur[srcl], 1);
        dst_sorted[slot] = dst;
        *(uint4*)(alpha16 + (size_t)slot * 8) = make_uint4(q[0], q[1], q[2], q[3]);
    }
}

// ---------------------------------------------------------------------------
// Gather + epilogue (R19): one wave per node, WAVE-UNIFORM addressing.
// readfirstlane(i) -> i/beg/end/e/dst all in SGPRs: row_ptr & dst_sorted
// load via s_load; h16 row base (d*128B) and alpha base (e*16B) fold into
// SGPR bases so the per-lane loads are saddr-form with constant voffsets.
// Per-edge VALU ~3 (cvt al, cvt h, fma); 8-deep unroll for loads-in-flight.
// ---------------------------------------------------------------------------
__global__ __launch_bounds__(256) void k_gather(
    const int* __restrict__ row_ptr, const int* __restrict__ dst_sorted,
    const __half* __restrict__ alpha16, const __half* __restrict__ h16,
    const float* __restrict__ x, const float* __restrict__ ln_scale,
    const float* __restrict__ ln_bias, float* __restrict__ out)
{
    const int i = __builtin_amdgcn_readfirstlane(
        blockIdx.x * 4 + (threadIdx.x >> 6));   // wave-uniform in SGPR
    if (i >= N_NODES) return;
    const int lane = threadIdx.x & 63;
    const int head = lane >> 3;

    const int beg = row_ptr[i];                  // s_load (uniform)
    const int end = row_ptr[i + 1];
    const float xres = x[(size_t)i * 64 + lane]; // saddr + lane*4

    float acc = 0.f;
    int e = beg;
    for (; e + 7 < end; e += 8) {
        int d[8];
        #pragma unroll
        for (int j = 0; j < 8; ++j) d[j] = dst_sorted[e + j];   // s_load x8
        float al[8];
        #pragma unroll
        for (int j = 0; j < 8; ++j)
            al[j] = __half2float(alpha16[(size_t)(e + j) * 8 + head]); // saddr
        float hv[8];
        #pragma unroll
        for (int j = 0; j < 8; ++j)
            hv[j] = __half2float(h16[(size_t)d[j] * 64 + lane]);       // saddr
        #pragma unroll
        for (int j = 0; j < 8; ++j) acc = fmaf(al[j], hv[j], acc);
    }
    for (; e + 3 < end; e += 4) {
        int d[4];
        #pragma unroll
        for (int j = 0; j < 4; ++j) d[j] = dst_sorted[e + j];
        float al[4];
        #pragma unroll
        for (int j = 0; j < 4; ++j)
            al[j] = __half2float(alpha16[(size_t)(e + j) * 8 + head]);
        float hv[4];
        #pragma unroll
        for (int j = 0; j < 4; ++j)
            hv[j] = __half2float(h16[(size_t)d[j] * 64 + lane]);
        #pragma unroll
        for (int j = 0; j < 4; ++j) acc = fmaf(al[j], hv[j], acc);
    }
    for (; e < end; ++e)
        acc = fmaf(__half2float(alpha16[(size_t)e * 8 + head]),
                   __half2float(h16[(size_t)dst_sorted[e] * 64 + lane]), acc);

    // epilogue: residual + LayerNorm + L2 normalize
    float v = acc + xres;
    float s = v;
    #pragma unroll
    for (int off = 1; off < 64; off <<= 1) s += __shfl_xor(s, off);
    const float mu = s * (1.f / 64.f);
    const float d = v - mu;
    float vs = d * d;
    #pragma unroll
    for (int off = 1; off < 64; off <<= 1) vs += __shfl_xor(vs, off);
    const float var = vs * (1.f / 64.f);
    float y = d * rsqrtf(var + LN_EPS) * ln_scale[lane] + ln_bias[lane];
    float ss = y * y;
    #pragma unroll
    for (int off = 1; off < 64; off <<= 1) ss += __shfl_xor(ss, off);
    const float norm = sqrtf(ss);
    out[(size_t)i * 64 + lane] = y / fmaxf(norm, NORM_EPS);
}

// ---------------------------------------------------------------------------
extern "C" void kernel_launch(void* const* d_in, const int* in_sizes, int n_in,
                              void* d_out, int out_size, void* d_ws, size_t ws_size,
                              hipStream_t stream)
{
    const float* x        = (const float*)d_in[0];
    const int*   ei       = (const int*)d_in[1];
    const float* W        = (const float*)d_in[2];
    const float* b        = (const float*)d_in[3];
    const float* a        = (const float*)d_in[4];
    const float* ln_scale = (const float*)d_in[5];
    const float* ln_bias  = (const float*)d_in[6];
    float* out = (float*)d_out;

    char* ws = (char*)d_ws;
    size_t off = 0;
    auto alloc = [&](size_t bytes) {
        void* p = ws + off;
        off = (off + bytes + 255) & ~(size_t)255;
        return p;
    };
    __half* h16        = (__half*)alloc((size_t)N_NODES * 64 * 2);
    float*  s_src      = (float*) alloc((size_t)N_NODES * 8 * 4);
    float*  s_dst      = (float*) alloc((size_t)N_NODES * 8 * 4);
    int*    bhist      = (int*)   alloc((size_t)NBKT * 4);
    int*    bucket_base= (int*)   alloc((size_t)(NBKT + 1) * 4);
    int*    gbin       = (int*)   alloc((size_t)NBKT * 4);
    int*    row_ptr    = (int*)   alloc((size_t)(N_NODES + 1) * 4);
    unsigned int* staged = (unsigned int*)alloc((size_t)N_EDGES * 4);
    int*    dst_sorted = (int*)   alloc((size_t)N_EDGES * 4);
    __half* alpha16    = (__half*)alloc((size_t)N_EDGES * 8 * 2);

    hipMemsetAsync(bhist, 0, (size_t)NBKT * 4, stream);

    k_hist  <<<BIN_BLOCKS, 1024, 0, stream>>>(ei, bhist);
    k_bscan <<<1, 1024, 0, stream>>>(bhist, bucket_base, gbin);
    k_gemm  <<<GEMM_BLOCKS, 256, 0, stream>>>(x, W, b, a, h16, s_src, s_dst);
    k_bin   <<<BIN_BLOCKS, 1024, 0, stream>>>(ei, gbin, staged);
    k_place <<<NBKT, 1024, 0, stream>>>(bucket_base, staged, s_src, s_dst,
                                        row_ptr, dst_sorted, alpha16);
    k_gather<<<(N_NODES + 3) / 4, 256, 0, stream>>>(row_ptr, dst_sorted, alpha16,
                                                    h16, x, ln_scale, ln_bias, out);
}